// Round 7
// baseline (301.596 us; speedup 1.0000x reference)
//
#include <hip/hip_runtime.h>

typedef _Float16 h8 __attribute__((ext_vector_type(8)));
typedef _Float16 h4 __attribute__((ext_vector_type(4)));
typedef float f32x4 __attribute__((ext_vector_type(4)));
typedef float f32x16 __attribute__((ext_vector_type(16)));

union HU { _Float16 h; unsigned short u; };
__device__ __forceinline__ unsigned short f2h(float f) { HU x; x.h = (_Float16)f; return x.u; }
__device__ __forceinline__ float h2f(unsigned short u) { HU x; x.u = u; return (float)x.h; }

#define MFMA16(a, b, c) __builtin_amdgcn_mfma_f32_16x16x32_f16((a), (b), (c), 0, 0, 0)
#define MFMA32(a, b, c) __builtin_amdgcn_mfma_f32_32x32x16_f16((a), (b), (c), 0, 0, 0)

// ---------------------------------------------------------------------------
// k_prep (grid-stride): pack MFMA B-fragments.
// 16x16x32 B-frag: lane holds B[k=(lane>>4)*8+j][n=lane&15]   (j=0..7)
// 32x32x16 B-frag: lane holds B[k=(lane>>5)*8+j][n=lane&31]
//  w1f  [f2][lane][8]   conv1, 16x16x32: f=0: k -> row r=k>>4 (0,1),
//        within=k&15, tx=within>>2, ch=within&3 (tx/ch==3 -> 0);
//        f=1: row2 via within=k (k>=16 -> 0). n = oc(16).
//  w2f  [tap9][lane][8]        conv2 32x32x16: k=ic(16), n=oc(32)
//  w3f  [nt2][tap9][kh2][lane][8] conv3 32x32x16: k=kh*16+..(ic32), n=nt*32+..
//  w1hd [kk19][nt12][lane][8]  heads L1 16x16x32 (k over 608, 584 used)
//  w2hd [kk4][nt4][lane][8]    heads L2
//  w3hd [kk4][lane][8]         heads L3 (n<2: ptw3; n==2: cfw2 at k>=64)
// ---------------------------------------------------------------------------
__global__ void k_prep(const float* __restrict__ w1, const float* __restrict__ w2,
                       const float* __restrict__ w3,
                       const float* __restrict__ ptw1, const float* __restrict__ cfw1,
                       const float* __restrict__ ptw2, const float* __restrict__ ptw3,
                       const float* __restrict__ cfw2,
                       unsigned short* __restrict__ w1f,
                       unsigned short* __restrict__ w2f,
                       unsigned short* __restrict__ w3f,
                       unsigned short* __restrict__ w1hd,
                       unsigned short* __restrict__ w2hd,
                       unsigned short* __restrict__ w3hd) {
    int gid = blockIdx.x * 256 + threadIdx.x;
    int gs = gridDim.x * 256;
    for (int e = gid; e < 1024; e += gs) {
        int f = e >> 9, lane = (e >> 3) & 63, j = e & 7;
        int k = ((lane >> 4) << 3) + j, oc = lane & 15;
        int r, within;
        if (f == 0) { r = k >> 4; within = k & 15; }
        else        { r = 2;      within = k; }
        int tx = within >> 2, ch = within & 3;
        float v = 0.f;
        if (tx < 3 && ch < 3) v = w1[oc * 27 + ch * 9 + r * 3 + tx];
        w1f[e] = f2h(v);
    }
    for (int e = gid; e < 4608; e += gs) {
        int t = e >> 9, lane = (e >> 3) & 63, j = e & 7;
        int ic = ((lane >> 5) << 3) + j, oc = lane & 31;
        w2f[e] = f2h(w2[oc * 144 + ic * 9 + t]);
    }
    for (int e = gid; e < 18432; e += gs) {
        int idx = e >> 9, lane = (e >> 3) & 63, j = e & 7;
        int nt = idx / 18, rem = idx % 18, t = rem >> 1, kh = rem & 1;
        int ic = kh * 16 + ((lane >> 5) << 3) + j, oc = nt * 32 + (lane & 31);
        w3f[e] = f2h(w3[oc * 288 + ic * 9 + t]);
    }
    for (int e = gid; e < 116736; e += gs) {
        int j = e & 7, lane = (e >> 3) & 63, idx = e >> 9;
        int nt = idx % 12, kk = idx / 12;
        int k = kk * 32 + ((lane >> 4) << 3) + j, n = nt * 16 + (lane & 15);
        float v = 0.f;
        if (k < 584) v = (n < 128) ? ptw1[k * 128 + n] : cfw1[k * 64 + (n - 128)];
        w1hd[e] = f2h(v);
    }
    for (int e = gid; e < 8192; e += gs) {
        int j = e & 7, lane = (e >> 3) & 63, idx = e >> 9;
        int nt = idx & 3, kk = idx >> 2;
        int k = kk * 32 + ((lane >> 4) << 3) + j, n = nt * 16 + (lane & 15);
        w2hd[e] = f2h(ptw2[k * 64 + n]);
    }
    for (int e = gid; e < 2048; e += gs) {
        int j = e & 7, lane = (e >> 3) & 63, kk = e >> 9;
        int k = kk * 32 + ((lane >> 4) << 3) + j, n = lane & 15;
        float v = 0.f;
        if (k < 64) { if (n < 2) v = ptw3[k * 2 + n]; }
        else        { if (n == 2) v = cfw2[k - 64]; }
        w3hd[e] = f2h(v);
    }
}

// ---------------------------------------------------------------------------
// k_convs: 32-sample tile per 256-thread block (4 waves).
// conv1: 2x 16x16x32 per position (rows 0,1 | row 2 of the 3x3 window),
//        A = 2xb64 from ch-padded board. conv2/conv3: 32x32x16 (M=32 samples,
//        N=32 oc, K=16 ic). LDS: BD[32][8r][8c][4ch] stride 260,
//        A1[32][36][16] stride 588, A2[32][9][32] stride 300 (overlays A1).
// ---------------------------------------------------------------------------
#define BDS 260
#define A1S 588
#define A2S 300
#define BDH (32 * BDS)
#define LDSTOT (BDH + 32 * A1S)   // 27136 hw = 54272 B -> 3 blocks/CU

template<int NP>
__device__ __forceinline__ void conv2_part(
    const unsigned short* A1, unsigned short* A2, const h8* W2r,
    float b2v, int pps, int col32, int e5)
{
    float pooled[NP][16];
    #pragma unroll
    for (int pi = 0; pi < NP; pi++)
        #pragma unroll
        for (int r = 0; r < 16; r++) pooled[pi][r] = 0.f;
    #pragma unroll
    for (int pi = 0; pi < NP; pi++) {
        const int pp = pps + pi;
        const int py = pp / 3, px = pp % 3;
        #pragma unroll
        for (int sub = 0; sub < 4; sub++) {
            const int y = py * 2 + (sub >> 1), x = px * 2 + (sub & 1);
            f32x16 acc = {};
            #pragma unroll
            for (int t = 0; t < 9; t++) {
                const int sy = y + t / 3 - 1, sx = x + t % 3 - 1;
                if (sy < 0 || sy >= 6 || sx < 0 || sx >= 6) continue;
                const int ah = col32 * A1S + (sy * 6 + sx) * 16 + e5 * 8;
                union { h8 v; h4 h[2]; } a;
                a.h[0] = *(const h4*)&A1[ah];
                a.h[1] = *(const h4*)&A1[ah + 4];
                acc = MFMA32(a.v, W2r[t], acc);
            }
            #pragma unroll
            for (int r = 0; r < 16; r++)
                pooled[pi][r] = fmaxf(pooled[pi][r], acc[r] + b2v);
        }
    }
    __syncthreads();   // all A1 reads (block-wide) done before A2 overlays
    #pragma unroll
    for (int pi = 0; pi < NP; pi++)
        #pragma unroll
        for (int r = 0; r < 16; r++) {
            int row = (r & 3) + 8 * (r >> 2) + 4 * e5;
            A2[row * A2S + (pps + pi) * 32 + col32] = f2h(pooled[pi][r]);
        }
}

template<int NPOS>
__device__ __forceinline__ void conv3_part(
    const unsigned short* A2, const unsigned short* w3f,
    float b3v0, float b3v1, int ps, int col32, int e5,
    long long g0, unsigned short* feats)
{
    #pragma unroll
    for (int pi = 0; pi < NPOS; pi++) {
        const int p = ps + pi;
        const int y = p / 3, x = p % 3;
        f32x16 acc0 = {}, acc1 = {};
        #pragma unroll
        for (int t = 0; t < 9; t++) {
            const int sy = y + t / 3 - 1, sx = x + t % 3 - 1;
            if (sy < 0 || sy >= 3 || sx < 0 || sx >= 3) continue;
            #pragma unroll
            for (int kh = 0; kh < 2; kh++) {
                const int ah = col32 * A2S + (sy * 3 + sx) * 32 + kh * 16 + e5 * 8;
                union { h8 v; h4 h[2]; } a;
                a.h[0] = *(const h4*)&A2[ah];
                a.h[1] = *(const h4*)&A2[ah + 4];
                h8 b0 = ((const h8*)w3f)[((0 * 9 + t) * 2 + kh) * 64 + (col32 | (e5 << 5))];
                h8 b1 = ((const h8*)w3f)[((1 * 9 + t) * 2 + kh) * 64 + (col32 | (e5 << 5))];
                acc0 = MFMA32(a.v, b0, acc0);
                acc1 = MFMA32(a.v, b1, acc1);
            }
        }
        #pragma unroll
        for (int r = 0; r < 16; r++) {
            int row = (r & 3) + 8 * (r >> 2) + 4 * e5;
            feats[(g0 + row) * 584 + col32 * 9 + p] = f2h(fmaxf(acc0[r] + b3v0, 0.f));
            feats[(g0 + row) * 584 + (32 + col32) * 9 + p] = f2h(fmaxf(acc1[r] + b3v1, 0.f));
        }
    }
}

__global__ __launch_bounds__(256, 3) void k_convs(
    const float* __restrict__ board,
    const float* __restrict__ b1, const float* __restrict__ b2,
    const float* __restrict__ b3, const float* __restrict__ qp,
    const unsigned short* __restrict__ w1f,
    const unsigned short* __restrict__ w2f,
    const unsigned short* __restrict__ w3f,
    unsigned short* __restrict__ feats)
{
    __shared__ unsigned short LDSH[LDSTOT];
    const int tid = threadIdx.x, wid = tid >> 6, lane = tid & 63;
    unsigned short* BD = LDSH;
    unsigned short* A1 = LDSH + BDH;
    unsigned short* A2 = A1;                       // overlay (barrier-protected)
    const long long g0 = (long long)blockIdx.x * 32;
    const int col16 = lane & 15, q = lane >> 4;
    const int col32 = lane & 31, e5 = lane >> 5;
    const f32x4 ZERO4 = {0.f, 0.f, 0.f, 0.f};

    // ---- zero + stage board fp32 -> fp16, ch-padded-4, pos-padded 8x8 ----
    for (int e = tid; e < BDH / 4; e += 256)
        ((unsigned long long*)BD)[e] = 0ULL;
    __syncthreads();
    for (int e = tid; e < 32 * 108; e += 256) {
        int ss = e / 108, r2 = e % 108, ch = r2 / 36, p = r2 % 36;
        float v = board[g0 * 108 + e];
        BD[ss * BDS + ((p / 6 + 1) * 8 + (p % 6) + 1) * 4 + ch] = f2h(v);
    }
    __syncthreads();

    // ---- quantum: one (sample, qubit) per thread ----
    {
        int ss = tid >> 3, qq = tid & 7;
        int p8a = ((qq / 6 + 1) * 8 + (qq % 6) + 1) * 4;
        int e2 = (qq + 1) & 7;
        int p8b = ((e2 / 6 + 1) * 8 + (e2 % 6) + 1) * 4;
        float xq = h2f(BD[ss * BDS + p8a]);
        float xn = h2f(BD[ss * BDS + p8b]);
        float st = 0.f;
        for (int l = 0; l < 3; l++) {
            float a0 = qp[l * 24 + qq * 3], a1 = qp[l * 24 + qq * 3 + 1],
                  a2 = qp[l * 24 + qq * 3 + 2];
            st = sinf(a0 * xq) * cosf(a1 * xn) + tanhf(a2 * st);
        }
        feats[(g0 + ss) * 584 + 576 + qq] = f2h(st);
    }

    // ---- conv1: jobs = (M-tile = wid&1) x (pos-half = wid>>1) ----
    {
        const int mt1 = wid & 1, ph = wid >> 1;
        h8 w1r0 = ((const h8*)w1f)[lane];
        h8 w1r1 = ((const h8*)w1f)[64 + lane];
        float b1v = b1[col16];
        const int bs = (mt1 * 16 + col16) * BDS;
        const int rsel = q >> 1, wo = (q & 1) * 8;
        for (int p = ph * 18; p < ph * 18 + 18; p++) {
            int y = p / 6, x = p % 6;
            int ab1 = bs + ((y + rsel) * 8 + x) * 4 + wo;
            int ab2 = bs + ((y + 2) * 8 + x) * 4 + wo;
            union { h8 v; h4 h[2]; } a1v, a2v;
            a1v.h[0] = *(const h4*)&BD[ab1]; a1v.h[1] = *(const h4*)&BD[ab1 + 4];
            a2v.h[0] = *(const h4*)&BD[ab2]; a2v.h[1] = *(const h4*)&BD[ab2 + 4];
            f32x4 c = MFMA16(a1v.v, w1r0, ZERO4);
            c = MFMA16(a2v.v, w1r1, c);
            #pragma unroll
            for (int r = 0; r < 4; r++)
                A1[(mt1 * 16 + q * 4 + r) * A1S + p * 16 + col16] =
                    f2h(fmaxf(c[r] + b1v, 0.f));
        }
    }
    __syncthreads();

    // ---- conv2 (+relu+pool): pooled cells 3/2/2/2 across waves ----
    {
        h8 W2r[9];
        #pragma unroll
        for (int t = 0; t < 9; t++) W2r[t] = ((const h8*)w2f)[t * 64 + lane];
        float b2v = b2[col32];
        if (wid == 0) conv2_part<3>(A1, A2, W2r, b2v, 0, col32, e5);
        else          conv2_part<2>(A1, A2, W2r, b2v, wid * 2 + 1, col32, e5);
    }
    __syncthreads();

    // ---- conv3: positions 3/2/2/2 across waves, both oc-halves per wave ----
    {
        float b3v0 = b3[col32], b3v1 = b3[32 + col32];
        if (wid == 0) conv3_part<3>(A2, w3f, b3v0, b3v1, 0, col32, e5, g0, feats);
        else          conv3_part<2>(A2, w3f, b3v0, b3v1, wid * 2 + 1, col32, e5, g0, feats);
    }
}

// ---------------------------------------------------------------------------
// k_heads: 256 threads (4 waves), 64 samples/block. L1: wave w does nt-tiles
// 3w..3w+2 x all 4 M-tiles (acc = 48 VGPR -> launch_bounds(256,4) -> 16
// waves/CU for load-latency hiding). Barrier, then wave w does L2/L3/epilogue
// for M-tile w (16 samples).
// ---------------------------------------------------------------------------
#define HSH 208

__global__ __launch_bounds__(256, 4) void k_heads(
    const unsigned short* __restrict__ feats,
    const unsigned short* __restrict__ w1hd,
    const unsigned short* __restrict__ w2hd,
    const unsigned short* __restrict__ w3hd,
    const float* __restrict__ ptb1, const float* __restrict__ ptb2,
    const float* __restrict__ ptb3, const float* __restrict__ cfb1,
    const float* __restrict__ cfb2,
    float* __restrict__ out)
{
    __shared__ unsigned short H[64 * HSH];
    __shared__ float O[64][4];

    const int tid = threadIdx.x, wid = tid >> 6, lane = tid & 63;
    const int col = lane & 15, q = lane >> 4;
    const long long s0 = (long long)blockIdx.x * 64;
    const f32x4 ZERO4 = {0.f, 0.f, 0.f, 0.f};

    // ---- layer 1 ----
    f32x4 acc[4][3];
    #pragma unroll
    for (int mt = 0; mt < 4; mt++)
        #pragma unroll
        for (int nt = 0; nt < 3; nt++) acc[mt][nt] = ZERO4;

    const unsigned short* fp[4];
    #pragma unroll
    for (int mt = 0; mt < 4; mt++)
        fp[mt] = feats + (s0 + mt * 16 + col) * 584 + q * 8;
    const h8* wp1 = (const h8*)w1hd;
    const int ntb = wid * 3;

    for (int kk = 0; kk < 19; kk++) {
        h8 a[4];
        #pragma unroll
        for (int mt = 0; mt < 4; mt++) a[mt] = *(const h8*)(fp[mt] + kk * 32);
        h8 b[3];
        #pragma unroll
        for (int nt = 0; nt < 3; nt++)
            b[nt] = wp1[(kk * 12 + ntb + nt) * 64 + lane];
        #pragma unroll
        for (int nt = 0; nt < 3; nt++)
            #pragma unroll
            for (int mt = 0; mt < 4; mt++)
                acc[mt][nt] = MFMA16(a[mt], b[nt], acc[mt][nt]);
    }

    #pragma unroll
    for (int nt = 0; nt < 3; nt++) {
        int ntg = ntb + nt;
        float bv = (ntg < 8) ? ptb1[ntg * 16 + col] : cfb1[(ntg - 8) * 16 + col];
        #pragma unroll
        for (int mt = 0; mt < 4; mt++)
            #pragma unroll
            for (int r = 0; r < 4; r++)
                H[(mt * 16 + q * 4 + r) * HSH + ntg * 16 + col] =
                    f2h(fmaxf(acc[mt][nt][r] + bv, 0.f));
    }
    __syncthreads();

    // ---- layer 2: wave's own 16 samples (rows rb..rb+15) ----
    const int rb = wid * 16;
    f32x4 acc2[4];
    #pragma unroll
    for (int nt = 0; nt < 4; nt++) acc2[nt] = ZERO4;
    const h8* wp2 = (const h8*)w2hd;
    #pragma unroll
    for (int kk = 0; kk < 4; kk++) {
        int off = kk * 32 + q * 8;
        h8 a = *(const h8*)&H[(rb + col) * HSH + off];
        #pragma unroll
        for (int nt = 0; nt < 4; nt++) {
            h8 b = wp2[(kk * 4 + nt) * 64 + lane];
            acc2[nt] = MFMA16(a, b, acc2[nt]);
        }
    }
    // h2 -> H cols 0..63 of own rows (own-wave reads done; rows disjoint)
    #pragma unroll
    for (int nt = 0; nt < 4; nt++) {
        float bv = ptb2[nt * 16 + col];
        #pragma unroll
        for (int r = 0; r < 4; r++)
            H[(rb + q * 4 + r) * HSH + nt * 16 + col] =
                f2h(fmaxf(acc2[nt][r] + bv, 0.f));
    }

    // ---- layer 3 ----
    f32x4 acc3 = ZERO4;
    #pragma unroll
    for (int kk = 0; kk < 4; kk++) {
        int base = (kk < 2) ? kk * 32 : kk * 32 + 64;
        h8 a = *(const h8*)&H[(rb + col) * HSH + base + q * 8];
        h8 b = ((const h8*)w3hd)[kk * 64 + lane];
        acc3 = MFMA16(a, b, acc3);
    }
    if (col < 3) {
        float bv = (col < 2) ? ptb3[col] : cfb2[0];
        #pragma unroll
        for (int r = 0; r < 4; r++)
            O[rb + q * 4 + r][col] = acc3[r] + bv;
    }

    if (lane < 16) {
        int s = rb + lane;
        float l0 = O[s][0], l1 = O[s][1], l2 = O[s][2];
        float m = fmaxf(l0, l1);
        float e0 = expf(l0 - m), e1 = expf(l1 - m);
        float inv = 1.f / (e0 + e1);
        float* op = out + (s0 + s) * 3;
        op[0] = e0 * inv;
        op[1] = e1 * inv;
        op[2] = 1.f / (1.f + expf(-l2));
    }
}

extern "C" void kernel_launch(void* const* d_in, const int* in_sizes, int n_in,
                              void* d_out, int out_size, void* d_ws, size_t ws_size,
                              hipStream_t stream) {
    const float* board = (const float*)d_in[0];
    const float* c1w  = (const float*)d_in[2];
    const float* c1b  = (const float*)d_in[3];
    const float* c2w  = (const float*)d_in[4];
    const float* c2b  = (const float*)d_in[5];
    const float* c3w  = (const float*)d_in[6];
    const float* c3b  = (const float*)d_in[7];
    const float* qp   = (const float*)d_in[8];
    const float* ptw1 = (const float*)d_in[9];
    const float* ptb1 = (const float*)d_in[10];
    const float* ptw2 = (const float*)d_in[11];
    const float* ptb2 = (const float*)d_in[12];
    const float* ptw3 = (const float*)d_in[13];
    const float* ptb3 = (const float*)d_in[14];
    const float* cfw1 = (const float*)d_in[15];
    const float* cfb1 = (const float*)d_in[16];
    const float* cfw2 = (const float*)d_in[17];
    const float* cfb2 = (const float*)d_in[18];
    float* out = (float*)d_out;

    int Btot = in_sizes[0] / 108;          // 65536

    // ws layout (bytes, 16B-aligned):
    //   0       w1f    2048
    //   2048    w2f    9216
    //   11264   w3f    36864
    //   48128   w1hd   233472
    //   281600  w2hd   16384
    //   297984  w3hd   4096
    //   302080  feats  Btot*584*2 (+64B tail for k>=584 over-reads)
    unsigned short* w1f   = (unsigned short*)d_ws;
    unsigned short* w2f   = (unsigned short*)((char*)d_ws + 2048);
    unsigned short* w3f   = (unsigned short*)((char*)d_ws + 11264);
    unsigned short* w1hd  = (unsigned short*)((char*)d_ws + 48128);
    unsigned short* w2hd  = (unsigned short*)((char*)d_ws + 281600);
    unsigned short* w3hd  = (unsigned short*)((char*)d_ws + 297984);
    unsigned short* feats = (unsigned short*)((char*)d_ws + 302080);

    hipLaunchKernelGGL(k_prep, dim3(64), dim3(256), 0, stream,
                       c1w, c2w, c3w, ptw1, cfw1, ptw2, ptw3, cfw2,
                       w1f, w2f, w3f, w1hd, w2hd, w3hd);
    hipLaunchKernelGGL(k_convs, dim3(Btot / 32), dim3(256), 0, stream,
                       board, c1b, c2b, c3b, qp, w1f, w2f, w3f, feats);
    hipLaunchKernelGGL(k_heads, dim3(Btot / 64), dim3(256), 0, stream,
                       feats, w1hd, w2hd, w3hd, ptb1, ptb2, ptb3, cfb1, cfb2,
                       out);
}

// Round 8
// 188.098 us; speedup vs baseline: 1.6034x; 1.6034x over previous
//
#include <hip/hip_runtime.h>

typedef _Float16 h8 __attribute__((ext_vector_type(8)));
typedef _Float16 h4 __attribute__((ext_vector_type(4)));
typedef float f32x4 __attribute__((ext_vector_type(4)));

union HU { _Float16 h; unsigned short u; };
__device__ __forceinline__ unsigned short f2h(float f) { HU x; x.h = (_Float16)f; return x.u; }
__device__ __forceinline__ float h2f(unsigned short u) { HU x; x.u = u; return (float)x.h; }

#define MFMA16(a, b, c) __builtin_amdgcn_mfma_f32_16x16x32_f16((a), (b), (c), 0, 0, 0)

// ---------------------------------------------------------------------------
// k_prep (grid-stride, 64 blocks): pack all MFMA B-fragments (round-6 proven).
// 16x16x32 B-frag: lane holds B[k=(lane>>4)*8+j][n=lane&15].
// ---------------------------------------------------------------------------
__global__ void k_prep(const float* __restrict__ w1, const float* __restrict__ w2,
                       const float* __restrict__ w3,
                       const float* __restrict__ ptw1, const float* __restrict__ cfw1,
                       const float* __restrict__ ptw2, const float* __restrict__ ptw3,
                       const float* __restrict__ cfw2,
                       unsigned short* __restrict__ w1f,
                       unsigned short* __restrict__ w2f,
                       unsigned short* __restrict__ w3f,
                       unsigned short* __restrict__ w1hd,
                       unsigned short* __restrict__ w2hd,
                       unsigned short* __restrict__ w3hd) {
    int gid = blockIdx.x * 256 + threadIdx.x;
    int gs = gridDim.x * 256;
    for (int e = gid; e < 512; e += gs) {
        int j = e & 7, lane = e >> 3;
        int k = ((lane >> 4) * 8) + j, oc = lane & 15;
        float v = 0.f;
        if (k < 27) { int t = k / 3, ic = k % 3; v = w1[oc * 27 + ic * 9 + t]; }
        w1f[e] = f2h(v);
    }
    for (int e = gid; e < 9216; e += gs) {
        int j = e & 7, lane = (e >> 3) & 63, fo = e >> 9;   // fo = t*2+ot
        int ot = fo & 1, t = fo >> 1;
        int k = ((lane >> 4) * 8) + j, oc = ot * 16 + (lane & 15);
        float v = (k < 16) ? w2[oc * 144 + k * 9 + t] : 0.f;
        w2f[e] = f2h(v);
    }
    for (int e = gid; e < 18432; e += gs) {
        int j = e & 7, lane = (e >> 3) & 63, fo = e >> 9;   // fo = (otp*9+t)*2+oti
        int oti = fo & 1, t = (fo >> 1) % 9, otp = (fo >> 1) / 9;
        int ic = ((lane >> 4) * 8) + j, oc = (otp * 2 + oti) * 16 + (lane & 15);
        w3f[e] = f2h(w3[oc * 288 + ic * 9 + t]);
    }
    for (int e = gid; e < 116736; e += gs) {
        int j = e & 7, lane = (e >> 3) & 63, idx = e >> 9;  // idx = kk*12+nt
        int nt = idx % 12, kk = idx / 12;
        int k = kk * 32 + ((lane >> 4) * 8) + j, n = nt * 16 + (lane & 15);
        float v = 0.f;
        if (k < 584) v = (n < 128) ? ptw1[k * 128 + n] : cfw1[k * 64 + (n - 128)];
        w1hd[e] = f2h(v);
    }
    for (int e = gid; e < 8192; e += gs) {
        int j = e & 7, lane = (e >> 3) & 63, idx = e >> 9;  // idx = kk*4+nt
        int nt = idx & 3, kk = idx >> 2;
        int k = kk * 32 + ((lane >> 4) * 8) + j, n = nt * 16 + (lane & 15);
        w2hd[e] = f2h(ptw2[k * 64 + n]);
    }
    for (int e = gid; e < 2048; e += gs) {
        int j = e & 7, lane = (e >> 3) & 63, kk = e >> 9;
        int k = kk * 32 + ((lane >> 4) * 8) + j, n = lane & 15;
        float v = 0.f;
        if (k < 64) { if (n < 2) v = ptw3[k * 2 + n]; }
        else        { if (n == 2) v = cfw2[k - 64]; }
        w3hd[e] = f2h(v);
    }
}

// ---------------------------------------------------------------------------
// k_fused: conv1->conv2->pool->conv3 (+quantum) AND both MLP heads, one block
// = 32 samples, 4 waves. feats NEVER touches HBM (lives in LDS "FT").
// Conv phase: two 16-sample groups (g = wid>>1), two waves each (w2 = wid&1),
// round-6 proven structure. Heads phase: L1 N-split 3 nt-tiles/wave.
// LDS overlays (halfwords):
//   region B @0     : A1_g (stride 584, @g*9856) / A2_g overlay -> FT
//                     (32 rows, stride 616; rows g*16.. exactly cover A2_g)
//   region A @19712 : BD_g (stride 194, @+g*3104) -> H (32 x 200) ; O @26112
// total 26368 hw = 52736 B -> 3 blocks/CU (12 waves/CU).
// ---------------------------------------------------------------------------
#define BDS 194
#define A1S 584
#define A2S 296
#define FTS 616
#define HSH 200
#define RA_OFF 19712
#define O_OFF 26112
#define LDSTOT 26368

template<int PP0, int PP1>
__device__ __forceinline__ void conv2_compute(
    const unsigned short* A1, const h8* W2r, float b2v0, float b2v1,
    int sA1, int q, float pooled[5][2][4])
{
    #pragma unroll
    for (int pi = 0; pi < PP1 - PP0; pi++) {
        const int pp = PP0 + pi;
        #pragma unroll
        for (int sub = 0; sub < 4; sub++) {
            const int y = (pp / 3) * 2 + (sub >> 1), x = (pp % 3) * 2 + (sub & 1);
            f32x4 acc0 = {0.f, 0.f, 0.f, 0.f}, acc1 = {0.f, 0.f, 0.f, 0.f};
            #pragma unroll
            for (int t = 0; t < 9; t++) {
                const int sy = y + t / 3 - 1, sx = x + t % 3 - 1;
                if (sy < 0 || sy >= 6 || sx < 0 || sx >= 6) continue;
                h8 a = *(const h8*)&A1[sA1 + (sy * 6 + sx) * 16 + (q & 1) * 8];
                acc0 = MFMA16(a, W2r[t * 2 + 0], acc0);
                acc1 = MFMA16(a, W2r[t * 2 + 1], acc1);
            }
            #pragma unroll
            for (int r = 0; r < 4; r++) {
                pooled[pi][0][r] = fmaxf(pooled[pi][0][r], acc0[r] + b2v0);
                pooled[pi][1][r] = fmaxf(pooled[pi][1][r], acc1[r] + b2v1);
            }
        }
    }
}

template<int PP0, int PP1>
__device__ __forceinline__ void conv2_store(
    unsigned short* A2, const float pooled[5][2][4], int q, int col)
{
    #pragma unroll
    for (int pi = 0; pi < PP1 - PP0; pi++)
        #pragma unroll
        for (int ot = 0; ot < 2; ot++)
            #pragma unroll
            for (int r = 0; r < 4; r++)
                A2[(q * 4 + r) * A2S + (PP0 + pi) * 32 + ot * 16 + col] =
                    f2h(pooled[pi][ot][r]);
}

__global__ __launch_bounds__(256, 3) void k_fused(
    const float* __restrict__ board,
    const float* __restrict__ b1, const float* __restrict__ b2,
    const float* __restrict__ b3, const float* __restrict__ qp,
    const unsigned short* __restrict__ w1f,
    const unsigned short* __restrict__ w2f,
    const unsigned short* __restrict__ w3f,
    const unsigned short* __restrict__ w1hd,
    const unsigned short* __restrict__ w2hd,
    const unsigned short* __restrict__ w3hd,
    const float* __restrict__ ptb1, const float* __restrict__ ptb2,
    const float* __restrict__ ptb3, const float* __restrict__ cfb1,
    const float* __restrict__ cfb2,
    float* __restrict__ out)
{
    __shared__ __align__(16) unsigned short LDSH[LDSTOT];
    const int tid = threadIdx.x, wid = tid >> 6, lane = tid & 63;
    const int g = wid >> 1, w2 = wid & 1;
    const int col = lane & 15, q = lane >> 4;
    const long long gg0 = (long long)blockIdx.x * 32;
    const f32x4 ZERO4 = {0.f, 0.f, 0.f, 0.f};

    unsigned short* A1 = LDSH + g * 9856;
    unsigned short* A2 = A1;                          // overlay (barriered)
    unsigned short* BD = LDSH + RA_OFF + g * 3104;
    unsigned short* Hb = LDSH + RA_OFF;               // overlays BD (dead)
    float* O = (float*)(LDSH + O_OFF);

    // ---- 1. zero BD region + A1 tail cols 576..583 (NaN-proofing) ----
    for (int e = tid; e < 1552; e += 256)
        ((unsigned long long*)LDSH)[4928 + e] = 0ULL;   // hw 19712..25920
    {
        int g2 = tid >> 7, r = (tid >> 3) & 15, z = tid & 7;
        LDSH[g2 * 9856 + r * A1S + 576 + z] = 0;
    }
    __syncthreads();

    // ---- 2. stage board fp32 -> fp16, pos-padded 8x8, ch-last ----
    for (int e = tid; e < 32 * 108; e += 256) {
        int ss = e / 108, r2 = e % 108, ch = r2 / 36, p = r2 % 36;
        float v = board[gg0 * 108 + e];
        LDSH[RA_OFF + (ss >> 4) * 3104 + (ss & 15) * BDS +
             ((p / 6 + 1) * 8 + (p % 6) + 1) * 3 + ch] = f2h(v);
    }
    __syncthreads();

    // ---- 3. quantum -> register (written into FT later) ----
    float qv;
    {
        int ss = tid >> 3, qq = tid & 7;
        int base = RA_OFF + (ss >> 4) * 3104 + (ss & 15) * BDS;
        int p8a = ((qq / 6 + 1) * 8 + (qq % 6) + 1) * 3;
        int e2 = (qq + 1) & 7;
        int p8b = ((e2 / 6 + 1) * 8 + (e2 % 6) + 1) * 3;
        float xq = h2f(LDSH[base + p8a]);
        float xn = h2f(LDSH[base + p8b]);
        float st = 0.f;
        for (int l = 0; l < 3; l++) {
            float a0 = qp[l * 24 + qq * 3], a1 = qp[l * 24 + qq * 3 + 1],
                  a2 = qp[l * 24 + qq * 3 + 2];
            st = sinf(a0 * xq) * cosf(a1 * xn) + tanhf(a2 * st);
        }
        qv = st;
    }

    // ---- 4. conv1: group g, position half w2 ----
    {
        int dlt[8];
        #pragma unroll
        for (int j = 0; j < 8; j++) {
            int k = q * 8 + j;
            if (k < 27) { int t = k / 3, c = k % 3;
                          dlt[j] = ((t / 3 - 1) * 8 + (t % 3 - 1)) * 3 + c; }
            else dlt[j] = 0;
        }
        h8 w1r = ((const h8*)w1f)[lane];
        float b1v = b1[col];
        const int sB = RA_OFF + g * 3104 + col * BDS;
        for (int p = w2 * 18; p < w2 * 18 + 18; p++) {
            int ab = sB + ((p / 6 + 1) * 8 + (p % 6) + 1) * 3;
            union { h8 v; _Float16 e[8]; } af;
            #pragma unroll
            for (int j = 0; j < 8; j++) { HU z; z.u = LDSH[ab + dlt[j]]; af.e[j] = z.h; }
            f32x4 c = MFMA16(af.v, w1r, ZERO4);
            #pragma unroll
            for (int r = 0; r < 4; r++)
                A1[(q * 4 + r) * A1S + p * 16 + col] = f2h(fmaxf(c[r] + b1v, 0.f));
        }
    }
    __syncthreads();

    // ---- 5. conv2 (+relu+pool), pooled cells 5/4 across the group's waves ----
    float pooled[5][2][4];
    #pragma unroll
    for (int pi = 0; pi < 5; pi++)
        #pragma unroll
        for (int ot = 0; ot < 2; ot++)
            #pragma unroll
            for (int r = 0; r < 4; r++) pooled[pi][ot][r] = 0.f;
    {
        h8 W2r[18];
        #pragma unroll
        for (int f = 0; f < 18; f++) W2r[f] = ((const h8*)w2f)[f * 64 + lane];
        float b2v0 = b2[col], b2v1 = b2[16 + col];
        const int sA1 = col * A1S;
        if (w2 == 0) conv2_compute<0, 5>(A1, W2r, b2v0, b2v1, sA1, q, pooled);
        else         conv2_compute<5, 9>(A1, W2r, b2v0, b2v1, sA1, q, pooled);
    }
    __syncthreads();
    if (w2 == 0) conv2_store<0, 5>(A2, pooled, q, col);
    else         conv2_store<5, 9>(A2, pooled, q, col);
    __syncthreads();

    // ---- 6. conv3 -> registers (otp = w2) ----
    f32x4 c3a[9], c3b[9];
    {
        const int otp = w2;
        const int sA2 = col * A2S;
        h8 W3r[18];
        #pragma unroll
        for (int f = 0; f < 18; f++)
            W3r[f] = ((const h8*)w3f)[(otp * 18 + f) * 64 + lane];
        #pragma unroll
        for (int p = 0; p < 9; p++) {
            const int y = p / 3, x = p % 3;
            f32x4 acc0 = ZERO4, acc1 = ZERO4;
            #pragma unroll
            for (int t = 0; t < 9; t++) {
                const int sy = y + t / 3 - 1, sx = x + t % 3 - 1;
                if (sy < 0 || sy >= 3 || sx < 0 || sx >= 3) continue;
                h8 a = *(const h8*)&A2[sA2 + (sy * 3 + sx) * 32 + q * 8];
                acc0 = MFMA16(a, W3r[t * 2 + 0], acc0);
                acc1 = MFMA16(a, W3r[t * 2 + 1], acc1);
            }
            c3a[p] = acc0; c3b[p] = acc1;
        }
    }
    __syncthreads();   // all A2 reads done before FT overlays region B

    // ---- 7. write FT (feats tile) + quantum + zero tail cols 584..615 ----
    {
        const int otp = w2;
        float b3v0 = b3[(otp * 2 + 0) * 16 + col];
        float b3v1 = b3[(otp * 2 + 1) * 16 + col];
        int oc0 = (otp * 2 + 0) * 16 + col, oc1 = (otp * 2 + 1) * 16 + col;
        #pragma unroll
        for (int p = 0; p < 9; p++)
            #pragma unroll
            for (int r = 0; r < 4; r++) {
                int row = g * 16 + q * 4 + r;
                LDSH[row * FTS + oc0 * 9 + p] = f2h(fmaxf(c3a[p][r] + b3v0, 0.f));
                LDSH[row * FTS + oc1 * 9 + p] = f2h(fmaxf(c3b[p][r] + b3v1, 0.f));
            }
        LDSH[(tid >> 3) * FTS + 576 + (tid & 7)] = f2h(qv);
        for (int e = tid; e < 1024; e += 256)
            LDSH[(e >> 5) * FTS + 584 + (e & 31)] = 0;
    }
    __syncthreads();

    // ---- 8. heads L1: K=608 (19 kk), wave does nt-tiles wid*3..+2, both mt ----
    {
        f32x4 acc[2][3];
        #pragma unroll
        for (int mt = 0; mt < 2; mt++)
            #pragma unroll
            for (int nt = 0; nt < 3; nt++) acc[mt][nt] = ZERO4;
        const h8* wp1 = (const h8*)w1hd;
        const int ntb = wid * 3;
        for (int kk = 0; kk < 19; kk++) {
            h8 a0 = *(const h8*)&LDSH[col * FTS + kk * 32 + q * 8];
            h8 a1 = *(const h8*)&LDSH[(16 + col) * FTS + kk * 32 + q * 8];
            h8 b[3];
            #pragma unroll
            for (int nt = 0; nt < 3; nt++)
                b[nt] = wp1[(kk * 12 + ntb + nt) * 64 + lane];
            #pragma unroll
            for (int nt = 0; nt < 3; nt++) {
                acc[0][nt] = MFMA16(a0, b[nt], acc[0][nt]);
                acc[1][nt] = MFMA16(a1, b[nt], acc[1][nt]);
            }
        }
        #pragma unroll
        for (int nt = 0; nt < 3; nt++) {
            int ntg = ntb + nt;
            float bv = (ntg < 8) ? ptb1[ntg * 16 + col] : cfb1[(ntg - 8) * 16 + col];
            #pragma unroll
            for (int mt = 0; mt < 2; mt++)
                #pragma unroll
                for (int r = 0; r < 4; r++)
                    Hb[(mt * 16 + q * 4 + r) * HSH + ntg * 16 + col] =
                        f2h(fmaxf(acc[mt][nt][r] + bv, 0.f));
        }
    }
    __syncthreads();

    // ---- 9. heads L2: nt = wid, both mt; read cols 0..127, write cols 0..63 ----
    {
        f32x4 acc2[2];
        acc2[0] = ZERO4; acc2[1] = ZERO4;
        const h8* wp2 = (const h8*)w2hd;
        const int nt2 = wid;
        #pragma unroll
        for (int kk = 0; kk < 4; kk++) {
            h8 a0 = *(const h8*)&Hb[col * HSH + kk * 32 + q * 8];
            h8 a1 = *(const h8*)&Hb[(16 + col) * HSH + kk * 32 + q * 8];
            h8 b = wp2[(kk * 4 + nt2) * 64 + lane];
            acc2[0] = MFMA16(a0, b, acc2[0]);
            acc2[1] = MFMA16(a1, b, acc2[1]);
        }
        __syncthreads();   // all L2 reads done before overwriting cols 0..63
        float bv2 = ptb2[nt2 * 16 + col];
        #pragma unroll
        for (int mt = 0; mt < 2; mt++)
            #pragma unroll
            for (int r = 0; r < 4; r++)
                Hb[(mt * 16 + q * 4 + r) * HSH + nt2 * 16 + col] =
                    f2h(fmaxf(acc2[mt][r] + bv2, 0.f));
    }
    __syncthreads();

    // ---- 10. heads L3 + epilogue: waves 0,1 handle mt = wid ----
    if (wid < 2) {
        const int mt = wid;
        f32x4 a3 = ZERO4;
        #pragma unroll
        for (int kk = 0; kk < 4; kk++) {
            int base = (kk < 2) ? kk * 32 : kk * 32 + 64;
            h8 a = *(const h8*)&Hb[(mt * 16 + col) * HSH + base + q * 8];
            h8 b = ((const h8*)w3hd)[kk * 64 + lane];
            a3 = MFMA16(a, b, a3);
        }
        if (col < 3) {
            float bv = (col < 2) ? ptb3[col] : cfb2[0];
            #pragma unroll
            for (int r = 0; r < 4; r++)
                O[(mt * 16 + q * 4 + r) * 4 + col] = a3[r] + bv;
        }
        if (lane < 16) {
            int s = mt * 16 + lane;
            float l0 = O[s * 4 + 0], l1 = O[s * 4 + 1], l2 = O[s * 4 + 2];
            float m = fmaxf(l0, l1);
            float e0 = expf(l0 - m), e1 = expf(l1 - m);
            float inv = 1.f / (e0 + e1);
            float* op = out + (gg0 + s) * 3;
            op[0] = e0 * inv;
            op[1] = e1 * inv;
            op[2] = 1.f / (1.f + expf(-l2));
        }
    }
}

extern "C" void kernel_launch(void* const* d_in, const int* in_sizes, int n_in,
                              void* d_out, int out_size, void* d_ws, size_t ws_size,
                              hipStream_t stream) {
    const float* board = (const float*)d_in[0];
    const float* c1w  = (const float*)d_in[2];
    const float* c1b  = (const float*)d_in[3];
    const float* c2w  = (const float*)d_in[4];
    const float* c2b  = (const float*)d_in[5];
    const float* c3w  = (const float*)d_in[6];
    const float* c3b  = (const float*)d_in[7];
    const float* qp   = (const float*)d_in[8];
    const float* ptw1 = (const float*)d_in[9];
    const float* ptb1 = (const float*)d_in[10];
    const float* ptw2 = (const float*)d_in[11];
    const float* ptb2 = (const float*)d_in[12];
    const float* ptw3 = (const float*)d_in[13];
    const float* ptb3 = (const float*)d_in[14];
    const float* cfw1 = (const float*)d_in[15];
    const float* cfb1 = (const float*)d_in[16];
    const float* cfw2 = (const float*)d_in[17];
    const float* cfb2 = (const float*)d_in[18];
    float* out = (float*)d_out;

    int Btot = in_sizes[0] / 108;          // 65536

    // ws layout (bytes): w1f@0(1K) w2f@1024(18K) w3f@19456(36K) w1hd@56320(228K)
    //                    w2hd@289792(16K) w3hd@306176(4K). No feats array!
    unsigned short* w1f   = (unsigned short*)d_ws;
    unsigned short* w2f   = (unsigned short*)((char*)d_ws + 1024);
    unsigned short* w3f   = (unsigned short*)((char*)d_ws + 19456);
    unsigned short* w1hd  = (unsigned short*)((char*)d_ws + 56320);
    unsigned short* w2hd  = (unsigned short*)((char*)d_ws + 289792);
    unsigned short* w3hd  = (unsigned short*)((char*)d_ws + 306176);

    hipLaunchKernelGGL(k_prep, dim3(64), dim3(256), 0, stream,
                       c1w, c2w, c3w, ptw1, cfw1, ptw2, ptw3, cfw2,
                       w1f, w2f, w3f, w1hd, w2hd, w3hd);
    hipLaunchKernelGGL(k_fused, dim3(Btot / 32), dim3(256), 0, stream,
                       board, c1b, c2b, c3b, qp, w1f, w2f, w3f,
                       w1hd, w2hd, w3hd, ptb1, ptb2, ptb3, cfb1, cfb2, out);
}